// Round 13
// baseline (17246.214 us; speedup 1.0000x reference)
//
#include <hip/hip_runtime.h>
#include <math.h>

#define NB 256
#define NN 256
#define NK 128
#define ND 256
#define NH 512
#define NT 1024

// output layout (floats): x | f_out | u | p_u
#define OUT_X 0
#define OUT_F 65536
#define OUT_U 131072
#define OUT_P 196608

// per-batch ws float offsets
#define EPB   65280            // E levels 1..8 (255*256)
#define SP6O  EPB              // bn6 spec: 4*256
#define S1O   (SP6O + 1024)    // 2*256
#define S2O   (S1O + 512)      // 4*256
#define S3O   (S2O + 1024)     // 8*256
#define LOFFI (S3O + 2048)     // 256 ints (decision-bit slabs)
#define BPB   (LOFFI + 256)

__host__ __device__ __forceinline__ int loff(int d) { return 256 - (1 << (9 - d)); }

// ---------------- G1 engines (proven R12 shapes) ----------------
// g1ks: KS=4 k-quarters (q=tid>>8) x 256 col-pairs (f2 weights); zero redundancy.
template <int R>
__device__ void g1ks(const float* __restrict__ Abuf, float* __restrict__ part,
                     const int tid, const float* __restrict__ W1) {
  const int q = tid >> 8;
  const int c0 = (tid & 255) << 1;
  const float* Wp = W1 + (size_t)(q * 128) * NH + c0;
  const float* Ar = Abuf + q * 128;
  float a0[R], a1[R];
#pragma unroll
  for (int r = 0; r < R; ++r) { a0[r] = 0.f; a1[r] = 0.f; }
  float2 n0 = *(const float2*)Wp;
  float2 n1 = *(const float2*)(Wp + NH);
  float2 n2 = *(const float2*)(Wp + 2 * NH);
  float2 n3 = *(const float2*)(Wp + 3 * NH);
#pragma unroll 2
  for (int kc = 0; kc < 124; kc += 4) {
    const float2 w0 = n0, w1 = n1, w2 = n2, w3 = n3;
    const float* Wn = Wp + (size_t)(kc + 4) * NH;
    n0 = *(const float2*)Wn;
    n1 = *(const float2*)(Wn + NH);
    n2 = *(const float2*)(Wn + 2 * NH);
    n3 = *(const float2*)(Wn + 3 * NH);
#pragma unroll
    for (int r = 0; r < R; ++r) {
      const float4 av = *(const float4*)(Ar + r * 512 + kc);
      a0[r] += av.x * w0.x + av.y * w1.x + av.z * w2.x + av.w * w3.x;
      a1[r] += av.x * w0.y + av.y * w1.y + av.z * w2.y + av.w * w3.y;
    }
  }
#pragma unroll
  for (int r = 0; r < R; ++r) {
    const float4 av = *(const float4*)(Ar + r * 512 + 124);
    a0[r] += av.x * n0.x + av.y * n1.x + av.z * n2.x + av.w * n3.x;
    a1[r] += av.x * n0.y + av.y * n1.y + av.z * n2.y + av.w * n3.y;
  }
#pragma unroll
  for (int r = 0; r < R; ++r)
    *(float2*)&part[(q * R + r) * 512 + c0] = make_float2(a0[r], a1[r]);
}

// g1q: KS=8 k-eighths (q=tid>>7) x 128 col-quads (f4 weights); zero redundancy.
template <int R>
__device__ void g1q(const float* __restrict__ Abuf, float* __restrict__ part,
                    const int tid, const float* __restrict__ W1) {
  const int q = tid >> 7;
  const int c0 = (tid & 127) << 2;
  const float* Wp = W1 + (size_t)(q * 64) * NH + c0;
  const float* Ar = Abuf + q * 64;
  float a0[R], a1[R], a2[R], a3[R];
#pragma unroll
  for (int r = 0; r < R; ++r) { a0[r] = 0.f; a1[r] = 0.f; a2[r] = 0.f; a3[r] = 0.f; }
  float4 n0 = *(const float4*)Wp;
  float4 n1 = *(const float4*)(Wp + NH);
  float4 n2 = *(const float4*)(Wp + 2 * NH);
  float4 n3 = *(const float4*)(Wp + 3 * NH);
#pragma unroll 2
  for (int kc = 0; kc < 60; kc += 4) {
    const float4 w0 = n0, w1 = n1, w2 = n2, w3 = n3;
    const float* Wn = Wp + (size_t)(kc + 4) * NH;
    n0 = *(const float4*)Wn;
    n1 = *(const float4*)(Wn + NH);
    n2 = *(const float4*)(Wn + 2 * NH);
    n3 = *(const float4*)(Wn + 3 * NH);
#pragma unroll
    for (int r = 0; r < R; ++r) {
      const float4 av = *(const float4*)(Ar + r * 512 + kc);
      a0[r] += av.x * w0.x + av.y * w1.x + av.z * w2.x + av.w * w3.x;
      a1[r] += av.x * w0.y + av.y * w1.y + av.z * w2.y + av.w * w3.y;
      a2[r] += av.x * w0.z + av.y * w1.z + av.z * w2.z + av.w * w3.z;
      a3[r] += av.x * w0.w + av.y * w1.w + av.z * w2.w + av.w * w3.w;
    }
  }
#pragma unroll
  for (int r = 0; r < R; ++r) {
    const float4 av = *(const float4*)(Ar + r * 512 + 60);
    a0[r] += av.x * n0.x + av.y * n1.x + av.z * n2.x + av.w * n3.x;
    a1[r] += av.x * n0.y + av.y * n1.y + av.z * n2.y + av.w * n3.y;
    a2[r] += av.x * n0.z + av.y * n1.z + av.z * n2.z + av.w * n3.z;
    a3[r] += av.x * n0.w + av.y * n1.w + av.z * n2.w + av.w * n3.w;
  }
#pragma unroll
  for (int r = 0; r < R; ++r)
    *(float4*)&part[(q * R + r) * 512 + c0] = make_float4(a0[r], a1[r], a2[r], a3[r]);
}

// ---------------- G2 engines ----------------
// g2ks: KS=8 k-eighths x 128 col-pairs; Hsrc row stride 512.
template <int R>
__device__ void g2ks(const float* __restrict__ Hsrc, float* __restrict__ part,
                     const int tid, const float* __restrict__ W2) {
  const int q = tid >> 7;
  const int c0 = (tid & 127) << 1;
  const float* Wp = W2 + (size_t)(q * 64) * ND + c0;
  const float* Hr = Hsrc + q * 64;
  float a0[R], a1[R];
#pragma unroll
  for (int r = 0; r < R; ++r) { a0[r] = 0.f; a1[r] = 0.f; }
  float2 n0 = *(const float2*)Wp;
  float2 n1 = *(const float2*)(Wp + ND);
  float2 n2 = *(const float2*)(Wp + 2 * ND);
  float2 n3 = *(const float2*)(Wp + 3 * ND);
#pragma unroll 2
  for (int kc = 0; kc < 60; kc += 4) {
    const float2 w0 = n0, w1 = n1, w2 = n2, w3 = n3;
    const float* Wn = Wp + (size_t)(kc + 4) * ND;
    n0 = *(const float2*)Wn;
    n1 = *(const float2*)(Wn + ND);
    n2 = *(const float2*)(Wn + 2 * ND);
    n3 = *(const float2*)(Wn + 3 * ND);
#pragma unroll
    for (int r = 0; r < R; ++r) {
      const float4 av = *(const float4*)(Hr + r * 512 + kc);
      a0[r] += av.x * w0.x + av.y * w1.x + av.z * w2.x + av.w * w3.x;
      a1[r] += av.x * w0.y + av.y * w1.y + av.z * w2.y + av.w * w3.y;
    }
  }
#pragma unroll
  for (int r = 0; r < R; ++r) {
    const float4 av = *(const float4*)(Hr + r * 512 + 60);
    a0[r] += av.x * n0.x + av.y * n1.x + av.z * n2.x + av.w * n3.x;
    a1[r] += av.x * n0.y + av.y * n1.y + av.z * n2.y + av.w * n3.y;
  }
#pragma unroll
  for (int r = 0; r < R; ++r)
    *(float2*)&part[(q * R + r) * 256 + c0] = make_float2(a0[r], a1[r]);
}

// g2q: KS=16 k-16ths x 64 col-quads (f4 weights).
template <int R>
__device__ void g2q(const float* __restrict__ Hsrc, float* __restrict__ part,
                    const int tid, const float* __restrict__ W2) {
  const int q = tid >> 6;
  const int c0 = (tid & 63) << 2;
  const float* Wp = W2 + (size_t)(q * 32) * ND + c0;
  const float* Hr = Hsrc + q * 32;
  float a0[R], a1[R], a2[R], a3[R];
#pragma unroll
  for (int r = 0; r < R; ++r) { a0[r] = 0.f; a1[r] = 0.f; a2[r] = 0.f; a3[r] = 0.f; }
  float4 n0 = *(const float4*)Wp;
  float4 n1 = *(const float4*)(Wp + ND);
  float4 n2 = *(const float4*)(Wp + 2 * ND);
  float4 n3 = *(const float4*)(Wp + 3 * ND);
#pragma unroll 2
  for (int kc = 0; kc < 28; kc += 4) {
    const float4 w0 = n0, w1 = n1, w2 = n2, w3 = n3;
    const float* Wn = Wp + (size_t)(kc + 4) * ND;
    n0 = *(const float4*)Wn;
    n1 = *(const float4*)(Wn + ND);
    n2 = *(const float4*)(Wn + 2 * ND);
    n3 = *(const float4*)(Wn + 3 * ND);
#pragma unroll
    for (int r = 0; r < R; ++r) {
      const float4 av = *(const float4*)(Hr + r * 512 + kc);
      a0[r] += av.x * w0.x + av.y * w1.x + av.z * w2.x + av.w * w3.x;
      a1[r] += av.x * w0.y + av.y * w1.y + av.z * w2.y + av.w * w3.y;
      a2[r] += av.x * w0.z + av.y * w1.z + av.z * w2.z + av.w * w3.z;
      a3[r] += av.x * w0.w + av.y * w1.w + av.z * w2.w + av.w * w3.w;
    }
  }
#pragma unroll
  for (int r = 0; r < R; ++r) {
    const float4 av = *(const float4*)(Hr + r * 512 + 28);
    a0[r] += av.x * n0.x + av.y * n1.x + av.z * n2.x + av.w * n3.x;
    a1[r] += av.x * n0.y + av.y * n1.y + av.z * n2.y + av.w * n3.y;
    a2[r] += av.x * n0.z + av.y * n1.z + av.z * n2.z + av.w * n3.z;
    a3[r] += av.x * n0.w + av.y * n1.w + av.z * n2.w + av.w * n3.w;
  }
#pragma unroll
  for (int r = 0; r < R; ++r)
    *(float4*)&part[(q * R + r) * 256 + c0] = make_float4(a0[r], a1[r], a2[r], a3[r]);
}

// ---------------- reduce phases ----------------
template <int KS, int R>
__device__ void g1red(const float* __restrict__ part, float* __restrict__ hid,
                      const int tid, const float* __restrict__ b1,
                      const int isBn, const float* __restrict__ embS,
                      const int* __restrict__ bitR) {
  for (int i = tid; i < R * 256; i += NT) {
    const int r = i >> 8, c0 = (i & 255) << 1;
    float2 s = *(const float2*)(b1 + c0);
#pragma unroll
    for (int qq = 0; qq < KS; ++qq) {
      const float2 p = *(const float2*)&part[(qq * R + r) * 512 + c0];
      s.x += p.x; s.y += p.y;
    }
    if (isBn) {
      const float2 e = *(const float2*)&embS[bitR[r] * 512 + c0];
      s.x += e.x; s.y += e.y;
    }
    *(float2*)&hid[r * 512 + c0] = make_float2(fmaxf(s.x, 0.f), fmaxf(s.y, 0.f));
  }
}

// spec reduce, split destination: output row o=2r+v -> d0 rows [0,splitRow), d1 after.
template <int KS, int R>
__device__ void g1redspec2(const float* __restrict__ part, float* __restrict__ d0,
                           float* __restrict__ d1, const int splitRow, const int tid,
                           const float* __restrict__ b1,
                           const float* __restrict__ embS) {
  for (int i = tid; i < R * 256; i += NT) {
    const int r = i >> 8, c0 = (i & 255) << 1;
    float2 s = *(const float2*)(b1 + c0);
#pragma unroll
    for (int qq = 0; qq < KS; ++qq) {
      const float2 p = *(const float2*)&part[(qq * R + r) * 512 + c0];
      s.x += p.x; s.y += p.y;
    }
    const float2 e0 = *(const float2*)&embS[c0];
    const float2 e1 = *(const float2*)&embS[512 + c0];
    const int o0 = 2 * r, o1 = 2 * r + 1;
    float* w0 = (o0 < splitRow) ? (d0 + (size_t)o0 * 512) : (d1 + (size_t)(o0 - splitRow) * 512);
    float* w1 = (o1 < splitRow) ? (d0 + (size_t)o1 * 512) : (d1 + (size_t)(o1 - splitRow) * 512);
    *(float2*)&w0[c0] = make_float2(fmaxf(s.x + e0.x, 0.f), fmaxf(s.y + e0.y, 0.f));
    *(float2*)&w1[c0] = make_float2(fmaxf(s.x + e1.x, 0.f), fmaxf(s.y + e1.y, 0.f));
  }
}

template <int KS, int R>
__device__ void g2red(const float* __restrict__ part, const int tid,
                      const float* __restrict__ b2,
                      float* const* __restrict__ rowDst) {
  for (int i = tid; i < R * 128; i += NT) {
    const int r = i >> 7, c0 = (i & 127) << 1;
    float2 s = *(const float2*)(b2 + c0);
#pragma unroll
    for (int qq = 0; qq < KS; ++qq) {
      const float2 p = *(const float2*)&part[(qq * R + r) * 256 + c0];
      s.x += p.x; s.y += p.y;
    }
    *(float2*)(rowDst[r] + c0) = s;
  }
}

__global__ __launch_bounds__(NT, 4) void sc_b2(
    const int* __restrict__ info_bits, const float* __restrict__ rv,
    const int* __restrict__ info_set,
    const float* __restrict__ obs_emb, const float* __restrict__ label_emb,
    const float* __restrict__ cnW1, const float* __restrict__ cnb1,
    const float* __restrict__ cnW2, const float* __restrict__ cnb2,
    const float* __restrict__ bnW1, const float* __restrict__ bnb1,
    const float* __restrict__ bnW2, const float* __restrict__ bnb2,
    const float* __restrict__ llrW, const float* __restrict__ llrb,
    float* __restrict__ out, float* __restrict__ ws) {
  __shared__ float A[5120];       // 10 staged rows (20 KB)
  __shared__ float partS[20480];  // k-split partials (80 KB); cascade overlays
  __shared__ float hid[10240];    // 20 hidden rows (40 KB)
  __shared__ float embS[1024];    // label_emb[bit] @ bnW1[512:768]
  __shared__ float rowBuf[256];
  __shared__ float* rowDst[16];
  __shared__ int fmap[256];
  __shared__ float red[16];
  __shared__ int bitR[8];
  __shared__ int qbS[8];          // [batch*4 + ph]

  const int tid = threadIdx.x;
  const int b0 = blockIdx.x * 2;
  float* wsb0 = ws + (size_t)b0 * BPB;
  float* wsb1 = ws + (size_t)(b0 + 1) * BPB;
  float* E0 = wsb0;               float* E1 = wsb1;
  float* sp6_0 = wsb0 + SP6O;     float* sp6_1 = wsb1 + SP6O;
  float* S1_0 = wsb0 + S1O;       float* S1_1 = wsb1 + S1O;
  float* S2_0 = wsb0 + S2O;       float* S2_1 = wsb1 + S2O;
  float* S3_0 = wsb0 + S3O;       float* S3_1 = wsb1 + S3O;
  int* Lb0 = (int*)(wsb0 + LOFFI); int* Lb1 = (int*)(wsb1 + LOFFI);
  const float* obs2 = obs_emb + 2 * ND;

  // ---- init: embC + fmap ----
  {
    const int bit = tid >> 9, col = tid & 511;
    float s = 0.f;
#pragma unroll 4
    for (int j = 0; j < ND; ++j)
      s += label_emb[bit * ND + j] * bnW1[(size_t)(NH + j) * NH + col];
    embS[bit * 512 + col] = s;
  }
  if (tid < 256) fmap[tid] = -1;
  __syncthreads();
  if (tid < NK) fmap[info_set[tid]] = tid;
  __syncthreads();

  // stage 2*CH rows: rows [0,CH) batch0 positions p0.., rows [CH,2CH) batch1.
  auto stagePlain = [&](int d, int p0, int CH) {
    const int n4 = 2 * CH * 128;
    for (int i = tid; i < n4; i += NT) {
      const int r = i >> 7, qq = i & 127, k = qq * 4;
      float4 v;
      if (d == 0) {
        v = *(const float4*)&obs2[k & 255];
      } else {
        const float* Eu = (r < CH) ? E0 : E1;
        const int p = p0 + ((r < CH) ? r : r - CH);
        v = *(const float4*)&Eu[(size_t)(loff(d) + 2 * p + (k >> 8)) * ND + (k & 255)];
      }
      *(float4*)&A[r * 512 + k] = v;
    }
  };

  // plain pass at depth d (cn or bn), both batches, CH=4 positions per chunk.
  auto plainPass = [&](int d, int isBn) {
    const int P = 1 << (7 - d);
    const float* W1 = isBn ? bnW1 : cnW1;
    const float* B1 = isBn ? bnb1 : cnb1;
    const float* W2 = isBn ? bnW2 : cnW2;
    const float* B2 = isBn ? bnb2 : cnb2;
    const int CH = (P >= 4) ? 4 : P;
    for (int p0 = 0; p0 < P; p0 += CH) {
      stagePlain(d, p0, CH);
      if (isBn && tid < 2 * CH) {
        const int batch = tid >= CH;
        const int p = p0 + (batch ? tid - CH : tid);
        bitR[tid] = (batch ? Lb1 : Lb0)[loff(d + 1) + p];
      }
      if (tid < 2 * CH) {
        const int batch = tid >= CH;
        const int p = p0 + (batch ? tid - CH : tid);
        rowDst[tid] = (batch ? E1 : E0) + (size_t)(loff(d + 1) + p) * ND;
      }
      __syncthreads();
      g1ks<8>(A, partS, tid, W1); __syncthreads();
      g1red<4, 8>(partS, hid, tid, B1, isBn, embS, bitR); __syncthreads();
      g2ks<8>(hid, partS, tid, W2); __syncthreads();
      g2red<8, 8>(partS, tid, B2, rowDst); __syncthreads();
    }
  };

  // uniform initial-descent pass: all rows identical for both batches.
  auto uniPass = [&](int d) {
    const int P = 1 << (7 - d);
    for (int i = tid; i < 128; i += NT) {
      const int k = (i & 127) * 4;
      float4 v;
      if (d == 0) v = *(const float4*)&obs2[k & 255];
      else v = *(const float4*)&E0[(size_t)(loff(d) + (k >> 8)) * ND + (k & 255)];
      *(float4*)&A[k] = v;
    }
    if (tid == 0) rowDst[0] = rowBuf;
    __syncthreads();
    g1q<1>(A, partS, tid, cnW1); __syncthreads();
    g1red<8, 1>(partS, hid, tid, cnb1, 0, embS, bitR); __syncthreads();
    g2q<1>(hid, partS, tid, cnW2); __syncthreads();
    g2red<16, 1>(partS, tid, cnb2, rowDst); __syncthreads();
    float* d0 = E0 + (size_t)loff(d + 1) * ND;
    float* d1 = E1 + (size_t)loff(d + 1) * ND;
    for (int i = tid; i < P * 256; i += NT) {
      const float v = rowBuf[i & 255];
      d0[i] = v; d1[i] = v;
    }
    __syncthreads();
  };

  // depth-6 pair, both batches: cn6 (4 rows -> E7) + bn6 spec (-> sp6_b[0..3])
  auto pair6 = [&]() {
    for (int i = tid; i < 4 * 128; i += NT) {
      const int r = i >> 7, qq = i & 127, k = qq * 4;
      const float* Eu = (r < 2) ? E0 : E1;
      const int rl = r & 1;
      *(float4*)&A[r * 512 + k] =
          *(const float4*)&Eu[(size_t)(248 + 2 * rl + (k >> 8)) * ND + (k & 255)];
    }
    if (tid < 4) {
      const int batch = tid >> 1, rl = tid & 1;
      rowDst[tid] = (batch ? E1 : E0) + (size_t)(252 + rl) * ND;
    }
    __syncthreads();
    g1q<4>(A, partS, tid, cnW1); __syncthreads();
    g1red<8, 4>(partS, hid, tid, cnb1, 0, embS, bitR); __syncthreads();
    g2q<4>(hid, partS, tid, cnW2); __syncthreads();
    g2red<16, 4>(partS, tid, cnb2, rowDst); __syncthreads();
    g1q<4>(A, partS, tid, bnW1); __syncthreads();
    // spec outputs: src r (2/batch) -> 2 variants each: hid rows 4..11
    g1redspec2<8, 4>(partS, hid + 4 * 512, hid, 8, tid, bnb1, embS); __syncthreads();
    g2ks<8>(hid + 4 * 512, partS, tid, bnW2);
    if (tid < 8) {
      const int batch = tid >> 2;
      rowDst[tid] = (batch ? sp6_1 : sp6_0) + (size_t)(tid & 3) * ND;
    }
    __syncthreads();
    g2red<8, 8>(partS, tid, bnb2, rowDst); __syncthreads();
  };

  // depth-7 combined, both batches: 10 A rows (5/batch).
  auto comb = [&]() {
    for (int i = tid; i < 10 * 128; i += NT) {
      const int r = i >> 7, qq = i & 127, k = qq * 4;
      const int h = k >> 8;
      const int batch = r >= 5;
      const int rl = batch ? r - 5 : r;
      const float* Eu = batch ? E1 : E0;
      const float* spu = batch ? sp6_1 : sp6_0;
      const float* src;
      if (rl == 0) src = Eu + (size_t)(252 + h) * ND;
      else {
        const int cc = rl - 1;
        const int bit = (h == 0) ? (cc >> 1) : (cc & 1);
        src = spu + (size_t)(h * 2 + bit) * ND;
      }
      *(float4*)&A[r * 512 + k] = *(const float4*)&src[k & 255];
    }
    __syncthreads();
    // cn side: 10 rows share one cnW1/cnW2 stream
    g1ks<10>(A, partS, tid, cnW1); __syncthreads();
    g1red<4, 10>(partS, hid, tid, cnb1, 0, embS, bitR); __syncthreads();
    g2ks<10>(hid, partS, tid, cnW2);
    if (tid < 10) {
      const int batch = tid >= 5;
      const int rl = batch ? tid - 5 : tid;
      float* Eu = batch ? E1 : E0;
      float* S2u = batch ? S2_1 : S2_0;
      rowDst[tid] = (rl == 0) ? (Eu + (size_t)254 * ND) : (S2u + (size_t)(rl - 1) * ND);
    }
    __syncthreads();
    g2red<8, 10>(partS, tid, cnb2, rowDst); __syncthreads();
    // bn side: 10 rows share one bnW1 stream -> 20 spec rows (10 in hid, 10 in A)
    g1ks<10>(A, partS, tid, bnW1); __syncthreads();
    g1redspec2<4, 10>(partS, hid + 10 * 512, A, 10, tid, bnb1, embS); __syncthreads();
    // batch0 outputs (rows 0..9 of spec = hid[10..19])
    g2ks<10>(hid + 10 * 512, partS, tid, bnW2);
    if (tid < 10) rowDst[tid] = (tid < 2) ? (S1_0 + (size_t)tid * ND)
                                          : (S3_0 + (size_t)(tid - 2) * ND);
    __syncthreads();
    g2red<8, 10>(partS, tid, bnb2, rowDst); __syncthreads();
    // batch1 outputs (rows 10..19 of spec = A[0..9])
    g2ks<10>(A, partS, tid, bnW2);
    if (tid < 10) rowDst[tid] = (tid < 2) ? (S1_1 + (size_t)tid * ND)
                                          : (S3_1 + (size_t)(tid - 2) * ND);
    __syncthreads();
    g2red<8, 10>(partS, tid, bnb2, rowDst); __syncthreads();
  };

  auto leaf = [&](int off) {
    const int ph = off & 3;
    if (tid < 512) {
      const int batch = tid >> 8, t = tid & 255;
      const float* Eu = batch ? E1 : E0;
      const float* S1u = batch ? S1_1 : S1_0;
      const float* S2u = batch ? S2_1 : S2_0;
      const float* S3u = batch ? S3_1 : S3_0;
      const int* qb = qbS + batch * 4;
      const float* src;
      if (ph == 0) src = Eu + (size_t)254 * ND;
      else if (ph == 1) src = S1u + (size_t)qb[0] * ND;
      else {
        const int cidx = 2 * (qb[0] ^ qb[1]) + qb[1];
        src = (ph == 2) ? (S2u + (size_t)cidx * ND)
                        : (S3u + (size_t)(2 * cidx + qb[2]) * ND);
      }
      const float ev = src[t];
      float v0 = ev * llrW[2 * t];
      float v1 = ev * llrW[2 * t + 1];
#pragma unroll
      for (int o = 32; o > 0; o >>= 1) {
        v0 += __shfl_down(v0, o);
        v1 += __shfl_down(v1, o);
      }
      const int w = tid >> 6;  // 0..7
      if ((tid & 63) == 0) { red[w] = v0; red[8 + w] = v1; }
    }
    __syncthreads();
    int* casc = (int*)partS;
    int* cur0 = casc;        int* nxt0 = casc + 256;
    int* cur1 = casc + 512;  int* nxt1 = casc + 768;
    if (tid < 512 && (tid & 255) == 0) {
      const int batch = tid >> 8;
      const int bg = b0 + batch;
      const float l0 = red[batch * 4 + 0] + red[batch * 4 + 1] +
                       red[batch * 4 + 2] + red[batch * 4 + 3] + llrb[0];
      const float l1 = red[8 + batch * 4 + 0] + red[8 + batch * 4 + 1] +
                       red[8 + batch * 4 + 2] + red[8 + batch * 4 + 3] + llrb[1];
      const float m = fmaxf(l0, l1);
      const float e0 = expf(l0 - m), e1 = expf(l1 - m);
      const float s = e0 + e1;
      const float p0 = e0 / s, p1 = e1 / s;
      const int hard = (rv[bg * NN + off] > p0) ? 1 : 0;
      const int fidx = fmap[off];
      const int fval = (fidx >= 0) ? info_bits[bg * NK + fidx] : 2;
      const int xb = (fval == 2) ? hard : fval;
      out[OUT_F + bg * NN + off] = (fidx >= 0) ? 2.0f : (float)xb;
      out[OUT_U + bg * NN + off] = (float)xb;
      out[OUT_P + (bg * NN + off) * 2 + 0] = p0;
      out[OUT_P + (bg * NN + off) * 2 + 1] = p1;
      (batch ? cur1 : cur0)[0] = xb;
      qbS[batch * 4 + ph] = xb;
    }
    __syncthreads();
    int len = 1, lev = 8, idx = off;
    while (idx & 1) {
      if (tid < 512) {
        const int batch = tid >> 8, t = tid & 255;
        int* cur = batch ? cur1 : cur0;
        int* nxt = batch ? nxt1 : nxt0;
        const int* Lbp = batch ? Lb1 : Lb0;
        if (t < len) {
          const int c = cur[t];
          nxt[2 * t] = Lbp[loff(lev) + t] ^ c;
          nxt[2 * t + 1] = c;
        }
      }
      __syncthreads();
      { int* t0 = cur0; cur0 = nxt0; nxt0 = t0; }
      { int* t1 = cur1; cur1 = nxt1; nxt1 = t1; }
      len <<= 1; idx >>= 1; --lev;
    }
    if (tid < 512) {
      const int batch = tid >> 8, t = tid & 255;
      int* cur = batch ? cur1 : cur0;
      int* Lbp = batch ? Lb1 : Lb0;
      if (lev > 0) {
        if (t < len) Lbp[loff(lev) + t] = cur[t];
      } else {
        out[OUT_X + (size_t)(b0 + batch) * NN + t] = (float)cur[t];
      }
    }
    __syncthreads();
  };

  // ---- initial descent (uniform across batches) ----
  for (int d = 0; d <= 5; ++d) uniPass(d);
  pair6();
  comb();

  // ---- leaf loop ----
  for (int off = 0; off < NN; ++off) {
    leaf(off);
    if (off == NN - 1) break;
    const int t = off + 1;
    const int z = __ffs(t) - 1;
    if (z <= 1) continue;  // inside a quad: everything pre-speculated
    const int dbn = 7 - z;  // <= 5
    plainPass(dbn, 1);
    for (int d = dbn + 1; d <= 5; ++d) plainPass(d, 0);
    pair6();
    comb();
  }
}

extern "C" void kernel_launch(void* const* d_in, const int* in_sizes, int n_in,
                              void* d_out, int out_size, void* d_ws, size_t ws_size,
                              hipStream_t stream) {
  const int*   info_bits = (const int*)d_in[0];
  const float* rv        = (const float*)d_in[1];
  const int*   info_set  = (const int*)d_in[2];
  const float* obs_emb   = (const float*)d_in[3];
  const float* label_emb = (const float*)d_in[4];
  const float* cnW1      = (const float*)d_in[5];
  const float* cnb1      = (const float*)d_in[6];
  const float* cnW2      = (const float*)d_in[7];
  const float* cnb2      = (const float*)d_in[8];
  const float* bnW1      = (const float*)d_in[9];
  const float* bnb1      = (const float*)d_in[10];
  const float* bnW2      = (const float*)d_in[11];
  const float* bnb2      = (const float*)d_in[12];
  const float* llrW      = (const float*)d_in[13];
  const float* llrb      = (const float*)d_in[14];

  float* out = (float*)d_out;
  float* ws  = (float*)d_ws;

  sc_b2<<<dim3(NB / 2), dim3(NT), 0, stream>>>(
      info_bits, rv, info_set, obs_emb, label_emb,
      cnW1, cnb1, cnW2, cnb2, bnW1, bnb1, bnW2, bnb2,
      llrW, llrb, out, ws);
}